// Round 2
// baseline (42.587 us; speedup 1.0000x reference)
//
#include <hip/hip_runtime.h>
#include <math.h>

// Problem constants (fixed by the reference)
constexpr int B_    = 8;
constexpr int CIN_  = 128;
constexpr int H_    = 28;
constexpr int W_    = 28;
constexpr int COUT_ = 256;
constexpr int OH_   = 28;
constexpr int OW_   = 28;
constexpr int L_    = OH_ * OW_;     // 784
constexpr int N_    = B_ * L_;       // 6272
constexpr int NCB_  = 64;
constexpr int K_    = 16;
constexpr int SUB_  = 18;            // 2 channels x 9 taps

// ---------------------------------------------------------------------------
// Phase 1: per (codebook, position) argmin over 16 centroids.
// dist = -2*round(xy/den) + round(y2/den).
// xy/den is EXACTLY the integer dot product of (x_q - x_z) and (c_q - c_z)
// (padded taps contribute 0, since padding is applied after dequant).
// y2/den computed in double (1024 values only).
// ---------------------------------------------------------------------------
__global__ __launch_bounds__(256) void amm_phase1(
    const int* __restrict__ x_q, const float* __restrict__ x_s, const int* __restrict__ x_z,
    const int* __restrict__ c_q, const float* __restrict__ c_s, const int* __restrict__ c_z,
    int* __restrict__ idx_out)
{
    const int cb  = blockIdx.x;
    const int tid = threadIdx.x;

    __shared__ int s_cq[K_][SUB_];
    __shared__ int s_iy2[K_];

    for (int i = tid; i < K_ * SUB_; i += 256)
        s_cq[i / SUB_][i % SUB_] = c_q[cb * K_ * SUB_ + i];
    __syncthreads();

    const int   zc  = c_z[cb];
    const float csf = c_s[cb];
    const float xsf = x_s[0];

    if (tid < K_) {
        double s2 = 0.0;
        for (int s = 0; s < SUB_; ++s) {
            double t = (double)(s_cq[tid][s] - zc) * (double)csf;
            s2 += t * t;
        }
        double v = s2 / ((double)xsf * (double)csf);
        s_iy2[tid] = (int)rint(v);
    }
    __syncthreads();

    const int n = blockIdx.y * 256 + tid;
    if (n >= N_) return;

    const int xz = x_z[0];
    const int b  = n / L_;
    const int r  = n - b * L_;
    const int oh = r / OW_;
    const int ow = r - oh * OW_;

    int xi[SUB_];
    int sx = 0;
    #pragma unroll
    for (int c2 = 0; c2 < 2; ++c2) {
        const int* base = x_q + (size_t)(b * CIN_ + 2 * cb + c2) * (H_ * W_);
        #pragma unroll
        for (int kh = 0; kh < 3; ++kh) {
            const int h = oh + kh - 1;
            #pragma unroll
            for (int kw = 0; kw < 3; ++kw) {
                const int w = ow + kw - 1;
                int v = 0;
                if ((unsigned)h < (unsigned)H_ && (unsigned)w < (unsigned)W_)
                    v = base[h * W_ + w] - xz;
                xi[c2 * 9 + kh * 3 + kw] = v;
                sx += v;
            }
        }
    }

    int bestd = 0x7fffffff, bestk = 0;
    #pragma unroll
    for (int k = 0; k < K_; ++k) {
        int dot = 0;
        #pragma unroll
        for (int s = 0; s < SUB_; ++s) dot += xi[s] * s_cq[k][s];
        const int ixy  = dot - zc * sx;          // = round(xy/den), exact integer
        const int dist = s_iy2[k] - 2 * ixy;
        if (dist < bestd) { bestd = dist; bestk = k; }  // strict < => first min
    }
    idx_out[cb * N_ + n] = bestk;
}

// ---------------------------------------------------------------------------
// Phase 2: out[n][co] = relu( (sum_cb lut_q[cb][idx][co] - 64*lz)*ls
//                             + (bias_q[co]-bz)*bs ), requantized to int8
// written as int32 (harness reads integer outputs as int32).
// Block = 4 positions x 64 lanes; each lane handles 4 couts via int4 loads.
// ---------------------------------------------------------------------------
__global__ __launch_bounds__(256) void amm_phase2(
    const int* __restrict__ idx_in, const int* __restrict__ lut_q,
    const float* __restrict__ lut_s, const int* __restrict__ lut_z,
    const int* __restrict__ bias_q, const float* __restrict__ bias_s,
    const int* __restrict__ bias_z,
    const float* __restrict__ out_s, const int* __restrict__ out_z,
    int* __restrict__ out)
{
    const int tid = threadIdx.x;
    const int nb  = blockIdx.x * 4;

    __shared__ int sidx[4][NCB_];
    {
        const int cbb = tid & 63, j = tid >> 6;
        sidx[j][cbb] = idx_in[cbb * N_ + nb + j];
    }
    __syncthreads();

    const int j    = tid >> 6;
    const int lane = tid & 63;
    const int n    = nb + j;

    const int4* lut4 = (const int4*)lut_q;
    int4 acc = {0, 0, 0, 0};
    #pragma unroll 8
    for (int cb = 0; cb < NCB_; ++cb) {
        const int k = sidx[j][cb];
        const int4 v = lut4[(cb * K_ + k) * 64 + lane];
        acc.x += v.x; acc.y += v.y; acc.z += v.z; acc.w += v.w;
    }

    const float lsf = lut_s[0];
    const int   lz  = lut_z[0];
    const float bsf = bias_s[0];
    const int   bz  = bias_z[0];
    const float osf = out_s[0];
    const float ozf = (float)out_z[0];

    const int b = n / L_;
    const int r = n - b * L_;

    const int accs[4] = {acc.x, acc.y, acc.z, acc.w};
    #pragma unroll
    for (int i = 0; i < 4; ++i) {
        const int co = lane * 4 + i;
        float sum = (float)(accs[i] - NCB_ * lz) * lsf
                  + (float)(bias_q[co] - bz) * bsf;
        float o = fmaxf(sum, 0.0f);                 // ReLU
        float v = o / osf + ozf;
        v = fminf(fmaxf(v, -128.0f), 127.0f);
        // jnp.round is half-to-even; rintf matches. Output dtype int8 -> int32 buffer.
        out[(size_t)(b * COUT_ + co) * L_ + r] = (int)rintf(v);
    }
}

extern "C" void kernel_launch(void* const* d_in, const int* in_sizes, int n_in,
                              void* d_out, int out_size, void* d_ws, size_t ws_size,
                              hipStream_t stream)
{
    const int*   x_q    = (const int*)  d_in[0];
    const float* x_s    = (const float*)d_in[1];
    const int*   x_z    = (const int*)  d_in[2];
    const int*   c_q    = (const int*)  d_in[3];
    const float* c_s    = (const float*)d_in[4];
    const int*   c_z    = (const int*)  d_in[5];
    const int*   lut_q  = (const int*)  d_in[6];
    const float* lut_s  = (const float*)d_in[7];
    const int*   lut_z  = (const int*)  d_in[8];
    const int*   bias_q = (const int*)  d_in[9];
    const float* bias_s = (const float*)d_in[10];
    const int*   bias_z = (const int*)  d_in[11];
    const float* out_s  = (const float*)d_in[12];
    const int*   out_z  = (const int*)  d_in[13];

    int* idx_ws = (int*)d_ws;  // 64 * 6272 * 4 B = 1.6 MB

    dim3 g1(NCB_, (N_ + 255) / 256);
    amm_phase1<<<g1, 256, 0, stream>>>(x_q, x_s, x_z, c_q, c_s, c_z, idx_ws);

    amm_phase2<<<dim3(N_ / 4), 256, 0, stream>>>(
        idx_ws, lut_q, lut_s, lut_z, bias_q, bias_s, bias_z,
        out_s, out_z, (int*)d_out);
}